// Round 1
// baseline (102.015 us; speedup 1.0000x reference)
//
#include <hip/hip_runtime.h>

#define N 1024
#define DD 256
#define EPS 100.0f
#define INV_EPS (1.0f / 100.0f)
#define LOG_MU -6.93147180559945f

__device__ __forceinline__ float blockReduceSum(float val, float* red) {
  const int t = threadIdx.x;
  red[t] = val;
  __syncthreads();
  for (int off = 128; off > 0; off >>= 1) {
    if (t < off) red[t] += red[t + off];
    __syncthreads();
  }
  return red[0];
}

// C[i][j] = sum_k |x[i][k] - y[j][k]|. 64x64 tile per block, 4x4 per thread,
// k-major LDS (transposed stage) so compute reads are float4 along rows/cols.
__global__ __launch_bounds__(256) void cmat_kernel(
    const float* __restrict__ x, const float* __restrict__ y,
    float* __restrict__ Cm, float* __restrict__ CT, int useCT,
    float* __restrict__ u, float* __restrict__ v, int* __restrict__ doneArr) {
  __shared__ float xs[32][68];
  __shared__ float ys[32][68];
  const int t = threadIdx.x;
  const int bi = blockIdx.y, bj = blockIdx.x;
  if (bi == 0 && bj == 0) {  // init duals + done flag (runs before iter kernels)
    for (int k = t; k < N; k += 256) { u[k] = 0.0f; v[k] = 0.0f; }
    if (t == 0) doneArr[0] = 0;
  }
  const int tx = t & 15, ty = t >> 4;
  float acc[4][4] = {};
  for (int kc = 0; kc < DD; kc += 32) {
#pragma unroll
    for (int rep = 0; rep < 2; ++rep) {
      const int lin = rep * 256 + t;  // 0..511
      const int row = lin >> 3;       // 0..63
      const int kq = lin & 7;         // which float4 of the 32-k chunk
      const float4 gx = *reinterpret_cast<const float4*>(
          x + (size_t)(bi * 64 + row) * DD + kc + kq * 4);
      xs[kq * 4 + 0][row] = gx.x; xs[kq * 4 + 1][row] = gx.y;
      xs[kq * 4 + 2][row] = gx.z; xs[kq * 4 + 3][row] = gx.w;
      const float4 gy = *reinterpret_cast<const float4*>(
          y + (size_t)(bj * 64 + row) * DD + kc + kq * 4);
      ys[kq * 4 + 0][row] = gy.x; ys[kq * 4 + 1][row] = gy.y;
      ys[kq * 4 + 2][row] = gy.z; ys[kq * 4 + 3][row] = gy.w;
    }
    __syncthreads();
#pragma unroll
    for (int k = 0; k < 32; ++k) {
      const float4 xv = *reinterpret_cast<const float4*>(&xs[k][ty * 4]);
      const float4 yv = *reinterpret_cast<const float4*>(&ys[k][tx * 4]);
      const float xr[4] = {xv.x, xv.y, xv.z, xv.w};
      const float yc[4] = {yv.x, yv.y, yv.z, yv.w};
#pragma unroll
      for (int r = 0; r < 4; ++r)
#pragma unroll
        for (int c = 0; c < 4; ++c) acc[r][c] += fabsf(xr[r] - yc[c]);
    }
    __syncthreads();
  }
#pragma unroll
  for (int r = 0; r < 4; ++r) {
    const int gr = bi * 64 + ty * 4 + r;
    const int gc0 = bj * 64 + tx * 4;
    *reinterpret_cast<float4*>(Cm + (size_t)gr * N + gc0) =
        make_float4(acc[r][0], acc[r][1], acc[r][2], acc[r][3]);
    if (useCT) {
#pragma unroll
      for (int c = 0; c < 4; ++c) CT[(size_t)(gc0 + c) * N + gr] = acc[r][c];
    }
  }
}

// u update: one block per row i. lse over j of (u_i + v_j - C_ij)/eps.
__global__ __launch_bounds__(256) void row_update_kernel(
    const float* __restrict__ Cm, float* __restrict__ u,
    const float* __restrict__ v, float* __restrict__ derr,
    const int* __restrict__ doneArr, int t_iter) {
  if (doneArr[t_iter]) return;
  __shared__ float red[256];
  const int i = blockIdx.x;
  const int t = threadIdx.x;
  const float ui = u[i];
  const float* row = Cm + (size_t)i * N;
  float s = 0.0f;
  for (int j = t; j < N; j += 256) s += expf((ui + v[j] - row[j]) * INV_EPS);
  const float tot = blockReduceSum(s, red);
  if (t == 0) {
    const float lse = logf(tot + 1e-6f);
    const float un = EPS * (LOG_MU - lse) + ui;
    derr[i] = fabsf(un - ui);
    u[i] = un;
  }
}

// err = sum(derr); done[t+1] = done[t] || err < 0.1
__global__ __launch_bounds__(256) void done_kernel(
    const float* __restrict__ derr, int* __restrict__ doneArr, int t_iter) {
  __shared__ float red[256];
  const int t = threadIdx.x;
  const float s = derr[t] + derr[t + 256] + derr[t + 512] + derr[t + 768];
  const float tot = blockReduceSum(s, red);
  if (t == 0) doneArr[t_iter + 1] = doneArr[t_iter] | (tot < 0.1f ? 1 : 0);
}

// v update: one block per column j. Uses updated u. base/colPitch/iStride
// abstract over CT (coalesced) vs strided C fallback.
__global__ __launch_bounds__(256) void col_update_kernel(
    const float* __restrict__ base, int colPitch, int iStride,
    const float* __restrict__ u, float* __restrict__ v,
    const int* __restrict__ doneArr, int t_iter) {
  if (doneArr[t_iter]) return;
  __shared__ float red[256];
  const int j = blockIdx.x;
  const int t = threadIdx.x;
  const float vj = v[j];
  const float* col = base + (size_t)j * colPitch;
  float s = 0.0f;
  for (int i = t; i < N; i += 256)
    s += expf((u[i] + vj - col[(size_t)i * iStride]) * INV_EPS);
  const float tot = blockReduceSum(s, red);
  if (t == 0) {
    const float lse = logf(tot + 1e-6f);
    v[j] = EPS * (LOG_MU - lse) + vj;
  }
}

// loss partials: per row i, sum_j exp(M_ij) * C_ij
__global__ __launch_bounds__(256) void loss_partial_kernel(
    const float* __restrict__ Cm, const float* __restrict__ u,
    const float* __restrict__ v, float* __restrict__ partials) {
  __shared__ float red[256];
  const int i = blockIdx.x;
  const int t = threadIdx.x;
  const float ui = u[i];
  const float* row = Cm + (size_t)i * N;
  float s = 0.0f;
  for (int j = t; j < N; j += 256) {
    const float c = row[j];
    s += expf((ui + v[j] - c) * INV_EPS) * c;
  }
  const float tot = blockReduceSum(s, red);
  if (t == 0) partials[i] = tot;
}

__global__ __launch_bounds__(256) void loss_final_kernel(
    const float* __restrict__ partials, float* __restrict__ out) {
  __shared__ float red[256];
  const int t = threadIdx.x;
  const float s =
      partials[t] + partials[t + 256] + partials[t + 512] + partials[t + 768];
  const float tot = blockReduceSum(s, red);
  if (t == 0) out[0] = tot;
}

extern "C" void kernel_launch(void* const* d_in, const int* in_sizes, int n_in,
                              void* d_out, int out_size, void* d_ws,
                              size_t ws_size, hipStream_t stream) {
  const float* x = (const float*)d_in[0];  // "output"
  const float* y = (const float*)d_in[1];  // "target"
  float* out = (float*)d_out;

  const size_t nn = (size_t)N * N;
  const size_t need_ct = (2 * nn + 4 * N) * sizeof(float) + 64 * sizeof(int);
  const int useCT = (ws_size >= need_ct) ? 1 : 0;

  float* Cm = (float*)d_ws;
  float* CT = Cm + nn;
  float* tail = useCT ? (CT + nn) : (Cm + nn);
  float* u = tail;
  float* v = u + N;
  float* derr = v + N;
  float* partials = derr + N;
  int* doneArr = (int*)(partials + N);

  cmat_kernel<<<dim3(16, 16), 256, 0, stream>>>(x, y, Cm, CT, useCT, u, v,
                                                doneArr);
  for (int it = 0; it < 10; ++it) {
    row_update_kernel<<<N, 256, 0, stream>>>(Cm, u, v, derr, doneArr, it);
    done_kernel<<<1, 256, 0, stream>>>(derr, doneArr, it);
    if (useCT)
      col_update_kernel<<<N, 256, 0, stream>>>(CT, N, 1, u, v, doneArr, it);
    else
      col_update_kernel<<<N, 256, 0, stream>>>(Cm, 1, N, u, v, doneArr, it);
  }
  loss_partial_kernel<<<N, 256, 0, stream>>>(Cm, u, v, partials);
  loss_final_kernel<<<1, 256, 0, stream>>>(partials, out);
}

// Round 2
// 76.568 us; speedup vs baseline: 1.3323x; 1.3323x over previous
//
#include <hip/hip_runtime.h>

#define N 1024
#define DD 256
#define EPS 100.0f
#define INV_EPS (1.0f / 100.0f)
#define LOG_MU -6.93147180559945f

// ---------------- cmat: C[i][j] = sum_k |x[i][k]-y[j][k]|, plus CT ---------
// 64x32 tile per block, grid (32,16)=512 blocks (2/CU), 256 threads.
// Row-major LDS staging (float4 writes), k-vectorized float4 compute reads.
__global__ __launch_bounds__(256) void cmat_kernel(
    const float* __restrict__ x, const float* __restrict__ y,
    float* __restrict__ Cm, float* __restrict__ CT, float* __restrict__ u,
    float* __restrict__ v, int* __restrict__ doneArr) {
  __shared__ float xs[64][68];
  __shared__ float ys[32][68];
  const int t = threadIdx.x;
  const int bj = blockIdx.x;  // column tile: 32 cols
  const int bi = blockIdx.y;  // row tile: 64 rows
  if (bi == 0 && bj == 0) {   // init duals + done flag (stream-ordered)
    float4 z = make_float4(0.f, 0.f, 0.f, 0.f);
    *reinterpret_cast<float4*>(u + t * 4) = z;
    *reinterpret_cast<float4*>(v + t * 4) = z;
    if (t == 0) doneArr[0] = 0;
  }
  const int tx = t & 15;   // col group: cols tx*2, tx*2+1
  const int ty = t >> 4;   // row group: rows ty*4 .. ty*4+3
  float acc[4][2] = {};
  const float* xg = x + (size_t)(bi * 64) * DD;
  const float* yg = y + (size_t)(bj * 32) * DD;
  const int c0 = tx * 2, c1 = tx * 2 + 1;
  const int yswz = ((c0 >> 3) & 1) << 2;  // same for c0 and c0+1 (c0 even)

  for (int kc = 0; kc < DD; kc += 64) {
    __syncthreads();
#pragma unroll
    for (int it = 0; it < 4; ++it) {  // stage x: 64 rows x 64 k
      const int l = it * 256 + t;
      const int row = l >> 4, kq = l & 15;
      const float4 g =
          *reinterpret_cast<const float4*>(xg + row * DD + kc + kq * 4);
      *reinterpret_cast<float4*>(&xs[row][kq * 4]) = g;
    }
#pragma unroll
    for (int it = 0; it < 2; ++it) {  // stage y: 32 rows x 64 k, bit2-XOR swz
      const int l = it * 256 + t;
      const int row = l >> 4, kq = l & 15;
      const float4 g =
          *reinterpret_cast<const float4*>(yg + row * DD + kc + kq * 4);
      const int col = (kq * 4) ^ (((row >> 3) & 1) << 2);
      *reinterpret_cast<float4*>(&ys[row][col]) = g;
    }
    __syncthreads();
#pragma unroll 2
    for (int kk = 0; kk < 64; kk += 4) {
      float4 xr[4];
#pragma unroll
      for (int r = 0; r < 4; ++r)
        xr[r] = *reinterpret_cast<const float4*>(&xs[ty * 4 + r][kk]);
      const float4 ya =
          *reinterpret_cast<const float4*>(&ys[c0][kk ^ yswz]);
      const float4 yb =
          *reinterpret_cast<const float4*>(&ys[c1][kk ^ yswz]);
#pragma unroll
      for (int r = 0; r < 4; ++r) {
        acc[r][0] += fabsf(xr[r].x - ya.x) + fabsf(xr[r].y - ya.y) +
                     fabsf(xr[r].z - ya.z) + fabsf(xr[r].w - ya.w);
        acc[r][1] += fabsf(xr[r].x - yb.x) + fabsf(xr[r].y - yb.y) +
                     fabsf(xr[r].z - yb.z) + fabsf(xr[r].w - yb.w);
      }
    }
  }
  // C write (coalesced float2)
  const int gr0 = bi * 64 + ty * 4;
  const int gc0 = bj * 32 + c0;
#pragma unroll
  for (int r = 0; r < 4; ++r)
    *reinterpret_cast<float2*>(Cm + (size_t)(gr0 + r) * N + gc0) =
        make_float2(acc[r][0], acc[r][1]);
  // CT via LDS transpose (reuse xs), then coalesced float4 stores
  __syncthreads();
#pragma unroll
  for (int r = 0; r < 4; ++r) {
    xs[c0][ty * 4 + r] = acc[r][0];
    xs[c1][ty * 4 + r] = acc[r][1];
  }
  __syncthreads();
#pragma unroll
  for (int it = 0; it < 2; ++it) {
    const int l = it * 256 + t;
    const int crow = l >> 4, cq = l & 15;  // crow: col of C (0..31)
    const float4 val = *reinterpret_cast<const float4*>(&xs[crow][cq * 4]);
    *reinterpret_cast<float4*>(CT + (size_t)(bj * 32 + crow) * N + bi * 64 +
                               cq * 4) = val;
  }
}

__device__ __forceinline__ float waveReduceSum(float s) {
#pragma unroll
  for (int m = 1; m <= 32; m <<= 1) s += __shfl_xor(s, m);
  return s;
}

// row update: one WAVE per row, grid 256 x 256thr, no __syncthreads.
__global__ __launch_bounds__(256) void row_update_kernel(
    const float* __restrict__ Cm, float* __restrict__ u,
    const float* __restrict__ v, float* __restrict__ derr,
    const int* __restrict__ doneArr, int it) {
  if (doneArr[it]) return;
  const int lane = threadIdx.x & 63;
  const int i = blockIdx.x * 4 + (threadIdx.x >> 6);
  const float ui = u[i];
  const float* row = Cm + (size_t)i * N;
  float s = 0.0f;
#pragma unroll
  for (int q = 0; q < 4; ++q) {
    const int j = (q * 64 + lane) * 4;
    const float4 c4 = *reinterpret_cast<const float4*>(row + j);
    const float4 v4 = *reinterpret_cast<const float4*>(v + j);
    s += expf((ui + v4.x - c4.x) * INV_EPS) +
         expf((ui + v4.y - c4.y) * INV_EPS) +
         expf((ui + v4.z - c4.z) * INV_EPS) +
         expf((ui + v4.w - c4.w) * INV_EPS);
  }
  s = waveReduceSum(s);
  if (lane == 0) {
    const float lse = logf(s + 1e-6f);
    const float un = EPS * (LOG_MU - lse) + ui;
    derr[i] = fabsf(un - ui);
    u[i] = un;
  }
}

// col update (+ folded done computation in block0/wave0). One wave per col.
__global__ __launch_bounds__(256) void col_update_kernel(
    const float* __restrict__ CT, const float* __restrict__ u,
    float* __restrict__ v, const float* __restrict__ derr,
    int* __restrict__ doneArr, int it) {
  const int lane = threadIdx.x & 63;
  const int w = threadIdx.x >> 6;
  const int done = doneArr[it];
  if (blockIdx.x == 0 && w == 0) {  // done[it+1] = done | (sum derr < 0.1)
    float e = 0.0f;
#pragma unroll
    for (int q = 0; q < 4; ++q) {
      const float4 d4 =
          *reinterpret_cast<const float4*>(derr + (q * 64 + lane) * 4);
      e += d4.x + d4.y + d4.z + d4.w;
    }
    e = waveReduceSum(e);
    if (lane == 0) doneArr[it + 1] = done | (e < 0.1f ? 1 : 0);
  }
  if (done) return;
  const int j = blockIdx.x * 4 + w;
  const float vj = v[j];
  const float* col = CT + (size_t)j * N;
  float s = 0.0f;
#pragma unroll
  for (int q = 0; q < 4; ++q) {
    const int i4 = (q * 64 + lane) * 4;
    const float4 c4 = *reinterpret_cast<const float4*>(col + i4);
    const float4 u4 = *reinterpret_cast<const float4*>(u + i4);
    s += expf((u4.x + vj - c4.x) * INV_EPS) +
         expf((u4.y + vj - c4.y) * INV_EPS) +
         expf((u4.z + vj - c4.z) * INV_EPS) +
         expf((u4.w + vj - c4.w) * INV_EPS);
  }
  s = waveReduceSum(s);
  if (lane == 0) {
    const float lse = logf(s + 1e-6f);
    v[j] = EPS * (LOG_MU - lse) + vj;
  }
}

// loss partials: one wave per row: sum_j exp(M_ij)*C_ij
__global__ __launch_bounds__(256) void loss_partial_kernel(
    const float* __restrict__ Cm, const float* __restrict__ u,
    const float* __restrict__ v, float* __restrict__ partials) {
  const int lane = threadIdx.x & 63;
  const int i = blockIdx.x * 4 + (threadIdx.x >> 6);
  const float ui = u[i];
  const float* row = Cm + (size_t)i * N;
  float s = 0.0f;
#pragma unroll
  for (int q = 0; q < 4; ++q) {
    const int j = (q * 64 + lane) * 4;
    const float4 c4 = *reinterpret_cast<const float4*>(row + j);
    const float4 v4 = *reinterpret_cast<const float4*>(v + j);
    s += expf((ui + v4.x - c4.x) * INV_EPS) * c4.x +
         expf((ui + v4.y - c4.y) * INV_EPS) * c4.y +
         expf((ui + v4.z - c4.z) * INV_EPS) * c4.z +
         expf((ui + v4.w - c4.w) * INV_EPS) * c4.w;
  }
  s = waveReduceSum(s);
  if (lane == 0) partials[i] = s;
}

__global__ __launch_bounds__(256) void loss_final_kernel(
    const float* __restrict__ partials, float* __restrict__ out) {
  __shared__ float red[4];
  const int t = threadIdx.x;
  const int lane = t & 63;
  const float4 p4 = *reinterpret_cast<const float4*>(partials + t * 4);
  float s = p4.x + p4.y + p4.z + p4.w;
  s = waveReduceSum(s);
  if (lane == 0) red[t >> 6] = s;
  __syncthreads();
  if (t == 0) out[0] = red[0] + red[1] + red[2] + red[3];
}

extern "C" void kernel_launch(void* const* d_in, const int* in_sizes, int n_in,
                              void* d_out, int out_size, void* d_ws,
                              size_t ws_size, hipStream_t stream) {
  const float* x = (const float*)d_in[0];  // "output"
  const float* y = (const float*)d_in[1];  // "target"
  float* out = (float*)d_out;

  const size_t nn = (size_t)N * N;
  float* Cm = (float*)d_ws;
  float* CT = Cm + nn;
  float* u = CT + nn;
  float* v = u + N;
  float* derr = v + N;
  float* partials = derr + N;
  int* doneArr = (int*)(partials + N);

  cmat_kernel<<<dim3(32, 16), 256, 0, stream>>>(x, y, Cm, CT, u, v, doneArr);
  for (int it = 0; it < 10; ++it) {
    row_update_kernel<<<256, 256, 0, stream>>>(Cm, u, v, derr, doneArr, it);
    col_update_kernel<<<256, 256, 0, stream>>>(CT, u, v, derr, doneArr, it);
  }
  loss_partial_kernel<<<256, 256, 0, stream>>>(Cm, u, v, partials);
  loss_final_kernel<<<1, 256, 0, stream>>>(partials, out);
}